// Round 2
// baseline (2472.053 us; speedup 1.0000x reference)
//
#include <hip/hip_runtime.h>
#include <hip/hip_bf16.h>
#include <math.h>

#define B_ 16
#define N_ 2048
#define C_ 512
#define H_ 8
#define D_ 64
#define M_ (B_ * N_)   // 32768

__device__ __forceinline__ float gelu_exact(float v) {
    return 0.5f * v * (1.0f + erff(v * 0.70710678118654752440f));
}

// OUT[m,o] = act( sum_c IN[m,c]*W[o,c] + bias[o] ), IN [M,512], W [512,512] row-major.
// Tiles: BM=BN=64, BK=32. 256 threads, 4x4 per thread.
// LDS k-major with row stride 68 floats -> ds_read_b128 fragment loads, conflict-free.
__global__ __launch_bounds__(256) void linear_kernel(
    const float* __restrict__ in, const float* __restrict__ w,
    const float* __restrict__ bias, float* __restrict__ out, int act)
{
    __shared__ float sA[32][68];
    __shared__ float sB[32][68];
    const int tid  = threadIdx.x;
    const int row0 = blockIdx.y * 64;
    const int col0 = blockIdx.x * 64;
    const int r0 = (tid >> 4) << 2;
    const int c0 = (tid & 15) << 2;
    const int lr = tid >> 3;          // 0..31
    const int lk = (tid & 7) << 2;    // 0,4,...,28
    float acc[4][4] = {{0.f}};
    for (int kt = 0; kt < C_; kt += 32) {
        #pragma unroll
        for (int it = 0; it < 2; ++it) {
            const int r = lr + it * 32;
            const float4 va = *(const float4*)(in + (size_t)(row0 + r) * C_ + kt + lk);
            sA[lk + 0][r] = va.x; sA[lk + 1][r] = va.y; sA[lk + 2][r] = va.z; sA[lk + 3][r] = va.w;
            const float4 vb = *(const float4*)(w + (size_t)(col0 + r) * C_ + kt + lk);
            sB[lk + 0][r] = vb.x; sB[lk + 1][r] = vb.y; sB[lk + 2][r] = vb.z; sB[lk + 3][r] = vb.w;
        }
        __syncthreads();
        #pragma unroll 8
        for (int kk = 0; kk < 32; ++kk) {
            const float4 a4 = *(const float4*)&sA[kk][r0];
            const float4 b4 = *(const float4*)&sB[kk][c0];
            const float av[4] = {a4.x, a4.y, a4.z, a4.w};
            const float bv[4] = {b4.x, b4.y, b4.z, b4.w};
            #pragma unroll
            for (int i = 0; i < 4; ++i) {
                #pragma unroll
                for (int j = 0; j < 4; ++j) {
                    acc[i][j] = fmaf(av[i], bv[j], acc[i][j]);
                }
            }
        }
        __syncthreads();
    }
    float bv[4] = {0.f, 0.f, 0.f, 0.f};
    if (bias) {
        const float4 b4 = *(const float4*)(bias + col0 + c0);
        bv[0] = b4.x; bv[1] = b4.y; bv[2] = b4.z; bv[3] = b4.w;
    }
    #pragma unroll
    for (int i = 0; i < 4; ++i) {
        float vals[4];
        #pragma unroll
        for (int j = 0; j < 4; ++j) {
            float v = acc[i][j] + bv[j];
            if (act == 1) v = gelu_exact(v);
            vals[j] = v;
        }
        float4 o4; o4.x = vals[0]; o4.y = vals[1]; o4.z = vals[2]; o4.w = vals[3];
        *(float4*)(out + (size_t)(row0 + r0 + i) * C_ + col0 + c0) = o4;
    }
}

// kk[bh][d][e] = sum_n k[b,n,64h+d]*k[b,n,64h+e]; ktv likewise with v. One WG per (b,h).
__global__ __launch_bounds__(256) void kkv_kernel(
    const float* __restrict__ k, const float* __restrict__ v,
    float* __restrict__ kkb, float* __restrict__ ktvb)
{
    __shared__ float sK[32][68];
    __shared__ float sV[32][68];
    const int bh = blockIdx.x;
    const int b = bh >> 3, h = bh & 7;
    const int tid = threadIdx.x;
    const int d0 = (tid >> 4) << 2;
    const int e0 = (tid & 15) << 2;
    const int lr = tid >> 4;          // 0..15
    const int lc = (tid & 15) << 2;   // 0..60
    const float* kb = k + (size_t)b * N_ * C_ + h * D_;
    const float* vb = v + (size_t)b * N_ * C_ + h * D_;
    float akk[4][4] = {{0.f}}, akv[4][4] = {{0.f}};
    for (int nc = 0; nc < N_; nc += 32) {
        #pragma unroll
        for (int it = 0; it < 2; ++it) {
            const int r = lr + it * 16;
            *(float4*)&sK[r][lc] = *(const float4*)(kb + (size_t)(nc + r) * C_ + lc);
            *(float4*)&sV[r][lc] = *(const float4*)(vb + (size_t)(nc + r) * C_ + lc);
        }
        __syncthreads();
        #pragma unroll 8
        for (int nn = 0; nn < 32; ++nn) {
            const float4 kd = *(const float4*)&sK[nn][d0];
            const float4 ke = *(const float4*)&sK[nn][e0];
            const float4 ve = *(const float4*)&sV[nn][e0];
            const float kdv[4] = {kd.x, kd.y, kd.z, kd.w};
            const float kev[4] = {ke.x, ke.y, ke.z, ke.w};
            const float vev[4] = {ve.x, ve.y, ve.z, ve.w};
            #pragma unroll
            for (int i = 0; i < 4; ++i) {
                #pragma unroll
                for (int j = 0; j < 4; ++j) {
                    akk[i][j] = fmaf(kdv[i], kev[j], akk[i][j]);
                    akv[i][j] = fmaf(kdv[i], vev[j], akv[i][j]);
                }
            }
        }
        __syncthreads();
    }
    #pragma unroll
    for (int i = 0; i < 4; ++i) {
        float4 o1; o1.x = akk[i][0]; o1.y = akk[i][1]; o1.z = akk[i][2]; o1.w = akk[i][3];
        *(float4*)(kkb + (size_t)bh * 4096 + (size_t)(d0 + i) * 64 + e0) = o1;
        float4 o2; o2.x = akv[i][0]; o2.y = akv[i][1]; o2.z = akv[i][2]; o2.w = akv[i][3];
        *(float4*)(ktvb + (size_t)bh * 4096 + (size_t)(d0 + i) * 64 + e0) = o2;
    }
}

// Gauss-Jordan on augmented [kk | ktv] (kk is SPD -> no pivoting), then softmax over
// rows (axis d) per column e. One WG (1 wave, 64 threads) per (b,h). Thread = column.
__global__ __launch_bounds__(64) void solve_kernel(
    const float* __restrict__ kkb, const float* __restrict__ ktvb,
    float* __restrict__ attn)
{
    __shared__ float Mg[64][130];
    __shared__ float fac[64];
    const int bh = blockIdx.x;
    const int j = threadIdx.x;
    for (int r = 0; r < 64; ++r) {
        Mg[r][j]      = kkb[(size_t)bh * 4096 + (size_t)r * 64 + j];
        Mg[r][64 + j] = ktvb[(size_t)bh * 4096 + (size_t)r * 64 + j];
    }
    __syncthreads();
    for (int i = 0; i < 64; ++i) {
        fac[j] = Mg[j][i];
        __syncthreads();
        const float pinv = 1.0f / fac[i];
        const float mia = Mg[i][j] * pinv;
        const float mib = Mg[i][64 + j] * pinv;
        Mg[i][j] = mia;
        Mg[i][64 + j] = mib;
        __syncthreads();
        for (int r = 0; r < 64; ++r) {
            if (r != i) {
                const float f = fac[r];
                Mg[r][j]      -= f * mia;
                Mg[r][64 + j] -= f * mib;
            }
        }
        __syncthreads();
    }
    // softmax over d (rows) for column e=j of the right half
    float mx = -1e30f;
    for (int r = 0; r < 64; ++r) mx = fmaxf(mx, Mg[r][64 + j]);
    float s = 0.f;
    for (int r = 0; r < 64; ++r) {
        const float e = expf(Mg[r][64 + j] - mx);
        Mg[r][64 + j] = e;
        s += e;
    }
    const float inv = 1.0f / s;
    for (int r = 0; r < 64; ++r)
        attn[(size_t)bh * 4096 + (size_t)r * 64 + j] = Mg[r][64 + j] * inv;
}

// o[n,e] = sum_d q[n,d] * attn[d,e], per (b,h), in-place on q. WG per (b,h,64-row block).
__global__ __launch_bounds__(256) void apply_kernel(
    float* __restrict__ q, const float* __restrict__ attn)
{
    __shared__ float sQT[64][68];  // [d][row]
    __shared__ float sAt[64][68];  // [d][e]
    const int t = blockIdx.x;
    const int nb = t & 31, h = (t >> 5) & 7, b = t >> 8;
    const int tid = threadIdx.x;
    const size_t base = ((size_t)(b * N_ + nb * 64)) * C_ + h * D_;
    const float* ap = attn + (size_t)(b * H_ + h) * 4096;
    {
        const int lr = tid >> 4, lc = (tid & 15) << 2;
        #pragma unroll
        for (int it = 0; it < 4; ++it) {
            const int dd = lr + it * 16;
            *(float4*)&sAt[dd][lc] = *(const float4*)(ap + (size_t)dd * 64 + lc);
        }
        const int qr = tid >> 2, qf = tid & 3;
        #pragma unroll
        for (int it = 0; it < 4; ++it) {
            const int cc = (qf + it * 4) << 2;
            const float4 a = *(const float4*)(q + base + (size_t)qr * C_ + cc);
            sQT[cc + 0][qr] = a.x; sQT[cc + 1][qr] = a.y;
            sQT[cc + 2][qr] = a.z; sQT[cc + 3][qr] = a.w;
        }
    }
    __syncthreads();
    const int r0 = (tid >> 4) << 2, e0 = (tid & 15) << 2;
    float acc[4][4] = {{0.f}};
    #pragma unroll 8
    for (int dd = 0; dd < 64; ++dd) {
        const float4 qa = *(const float4*)&sQT[dd][r0];
        const float4 av = *(const float4*)&sAt[dd][e0];
        const float qv[4] = {qa.x, qa.y, qa.z, qa.w};
        const float aw[4] = {av.x, av.y, av.z, av.w};
        #pragma unroll
        for (int i = 0; i < 4; ++i) {
            #pragma unroll
            for (int j = 0; j < 4; ++j) {
                acc[i][j] = fmaf(qv[i], aw[j], acc[i][j]);
            }
        }
    }
    #pragma unroll
    for (int i = 0; i < 4; ++i) {
        float4 o4; o4.x = acc[i][0]; o4.y = acc[i][1]; o4.z = acc[i][2]; o4.w = acc[i][3];
        *(float4*)(q + base + (size_t)(r0 + i) * C_ + e0) = o4;
    }
}

// LayerNorm over last dim (512), in place. 1 wave per row, 4 rows per WG.
__global__ __launch_bounds__(256) void ln_kernel(
    float* __restrict__ o, const float* __restrict__ w, const float* __restrict__ bias)
{
    const int wv   = threadIdx.x >> 6;
    const int lane = threadIdx.x & 63;
    const size_t m = (size_t)blockIdx.x * 4 + wv;
    float* p = o + m * C_ + lane * 8;
    float4 v0 = *(const float4*)p;
    float4 v1 = *(const float4*)(p + 4);
    float s = v0.x + v0.y + v0.z + v0.w + v1.x + v1.y + v1.z + v1.w;
    float q = v0.x * v0.x + v0.y * v0.y + v0.z * v0.z + v0.w * v0.w
            + v1.x * v1.x + v1.y * v1.y + v1.z * v1.z + v1.w * v1.w;
    #pragma unroll
    for (int off = 1; off < 64; off <<= 1) {
        s += __shfl_xor(s, off, 64);
        q += __shfl_xor(q, off, 64);
    }
    const float mean = s * (1.0f / C_);
    const float var  = q * (1.0f / C_) - mean * mean;
    const float rstd = rsqrtf(var + 1e-6f);
    const float4 w0 = *(const float4*)(w + lane * 8);
    const float4 w1 = *(const float4*)(w + lane * 8 + 4);
    const float4 b0 = *(const float4*)(bias + lane * 8);
    const float4 b1 = *(const float4*)(bias + lane * 8 + 4);
    v0.x = (v0.x - mean) * rstd * w0.x + b0.x;
    v0.y = (v0.y - mean) * rstd * w0.y + b0.y;
    v0.z = (v0.z - mean) * rstd * w0.z + b0.z;
    v0.w = (v0.w - mean) * rstd * w0.w + b0.w;
    v1.x = (v1.x - mean) * rstd * w1.x + b1.x;
    v1.y = (v1.y - mean) * rstd * w1.y + b1.y;
    v1.z = (v1.z - mean) * rstd * w1.z + b1.z;
    v1.w = (v1.w - mean) * rstd * w1.w + b1.w;
    *(float4*)p = v0;
    *(float4*)(p + 4) = v1;
}

// g[m,c] = (sum_t a[b, n+t-5, c]*dw[c,t] + db[c]) * vv[m,c], zero padded per batch.
__global__ __launch_bounds__(256) void dwmul_kernel(
    const float* __restrict__ a, const float* __restrict__ vv,
    const float* __restrict__ dw, const float* __restrict__ db,
    float* __restrict__ g)
{
    const int gid = blockIdx.x * 256 + threadIdx.x;
    const int m = gid >> 7;
    const int c = (gid & 127) << 2;
    const int b = m >> 11;
    const int n = m & 2047;
    const float4 db4 = *(const float4*)(db + c);
    float accx = db4.x, accy = db4.y, accz = db4.z, accw = db4.w;
    const float* abase = a + ((size_t)b * N_) * C_ + c;
    #pragma unroll
    for (int t = 0; t < 11; ++t) {
        const int nn = n + t - 5;
        if (nn >= 0 && nn < N_) {
            const float4 a4 = *(const float4*)(abase + (size_t)nn * C_);
            accx = fmaf(a4.x, dw[(c + 0) * 11 + t], accx);
            accy = fmaf(a4.y, dw[(c + 1) * 11 + t], accy);
            accz = fmaf(a4.z, dw[(c + 2) * 11 + t], accz);
            accw = fmaf(a4.w, dw[(c + 3) * 11 + t], accw);
        }
    }
    const float4 v4 = *(const float4*)(vv + (size_t)m * C_ + c);
    float4 o4;
    o4.x = accx * v4.x; o4.y = accy * v4.y; o4.z = accz * v4.z; o4.w = accw * v4.w;
    *(float4*)(g + (size_t)m * C_ + c) = o4;
}

extern "C" void kernel_launch(void* const* d_in, const int* in_sizes, int n_in,
                              void* d_out, int out_size, void* d_ws, size_t ws_size,
                              hipStream_t stream)
{
    (void)in_sizes; (void)n_in; (void)out_size; (void)ws_size;
    const float* x      = (const float*)d_in[0];
    const float* wq     = (const float*)d_in[1];
    const float* wk     = (const float*)d_in[2];
    const float* wv     = (const float*)d_in[3];
    const float* ln_w   = (const float*)d_in[4];
    const float* ln_b   = (const float*)d_in[5];
    const float* ava1_w = (const float*)d_in[6];
    const float* ava1_b = (const float*)d_in[7];
    const float* dw_w   = (const float*)d_in[8];
    const float* dw_b   = (const float*)d_in[9];
    const float* v_w    = (const float*)d_in[10];
    const float* v_b    = (const float*)d_in[11];
    const float* proj_w = (const float*)d_in[12];
    const float* proj_b = (const float*)d_in[13];
    const float* out_w  = (const float*)d_in[14];
    const float* out_b  = (const float*)d_in[15];

    float* ws    = (float*)d_ws;
    float* kbuf  = ws;                                   // 64 MB  (k, then a, then p)
    float* vbuf  = ws + (size_t)M_ * C_;                 // 64 MB  (v, then vv)
    float* kkb   = ws + 2ULL * M_ * C_;                  // 2 MB
    float* ktvb  = kkb + 128ULL * 4096;                  // 2 MB
    float* attnb = ktvb + 128ULL * 4096;                 // 2 MB
    float* qbuf  = (float*)d_out;                        // q -> o -> o_ln -> g -> final out

    dim3 gg(C_ / 64, M_ / 64);  // (8, 512)
    linear_kernel<<<gg, 256, 0, stream>>>(x, wq, nullptr, qbuf, 0);
    linear_kernel<<<gg, 256, 0, stream>>>(x, wk, nullptr, kbuf, 0);
    linear_kernel<<<gg, 256, 0, stream>>>(x, wv, nullptr, vbuf, 0);
    kkv_kernel<<<B_ * H_, 256, 0, stream>>>(kbuf, vbuf, kkb, ktvb);
    solve_kernel<<<B_ * H_, 64, 0, stream>>>(kkb, ktvb, attnb);
    apply_kernel<<<B_ * H_ * (N_ / 64), 256, 0, stream>>>(qbuf, attnb);
    ln_kernel<<<M_ / 4, 256, 0, stream>>>(qbuf, ln_w, ln_b);
    linear_kernel<<<gg, 256, 0, stream>>>(qbuf, ava1_w, ava1_b, kbuf, 1);   // a = gelu(...)
    linear_kernel<<<gg, 256, 0, stream>>>(qbuf, v_w, v_b, vbuf, 0);         // vv
    dwmul_kernel<<<(M_ * 128) / 256, 256, 0, stream>>>(kbuf, vbuf, dw_w, dw_b, qbuf); // g
    linear_kernel<<<gg, 256, 0, stream>>>(qbuf, proj_w, proj_b, kbuf, 0);   // p
    linear_kernel<<<gg, 256, 0, stream>>>(kbuf, out_w, out_b, qbuf, 0);     // final -> d_out
}

// Round 3
// 838.493 us; speedup vs baseline: 2.9482x; 2.9482x over previous
//
#include <hip/hip_runtime.h>
#include <hip/hip_bf16.h>
#include <math.h>

#define B_ 16
#define N_ 2048
#define C_ 512
#define H_ 8
#define D_ 64
#define M_ (B_ * N_)   // 32768

typedef __attribute__((ext_vector_type(8))) __bf16 bf16x8;
typedef __attribute__((ext_vector_type(4))) float f32x4;
typedef __attribute__((ext_vector_type(4))) unsigned short u16x4;
typedef __attribute__((ext_vector_type(8))) unsigned short u16x8;

__device__ __forceinline__ float gelu_exact(float v) {
    return 0.5f * v * (1.0f + erff(v * 0.70710678118654752440f));
}
__device__ __forceinline__ unsigned short f2b(float f) {  // f32 -> bf16 RNE
    unsigned u = __float_as_uint(f);
    return (unsigned short)((u + 0x7fffu + ((u >> 16) & 1u)) >> 16);
}
__device__ __forceinline__ float b2f(unsigned short b) {
    return __uint_as_float(((unsigned)b) << 16);
}

// ---- f32 -> bf16 converters ----
__global__ __launch_bounds__(256) void convx_kernel(
    const float* __restrict__ src, unsigned short* __restrict__ dst)
{
    const size_t i = ((size_t)blockIdx.x * 256 + threadIdx.x) * 4;
    const float4 v = *(const float4*)(src + i);
    u16x4 o; o.x = f2b(v.x); o.y = f2b(v.y); o.z = f2b(v.z); o.w = f2b(v.w);
    *(u16x4*)(dst + i) = o;
}

__global__ __launch_bounds__(256) void convw_kernel(
    const float* w0, const float* w1, const float* w2, const float* w3,
    const float* w4, const float* w5, const float* w6, unsigned short* __restrict__ dst)
{
    const float* srcs[7] = {w0, w1, w2, w3, w4, w5, w6};
    const float* s = srcs[blockIdx.y];
    unsigned short* d = dst + (size_t)blockIdx.y * (C_ * C_);
    const size_t i = ((size_t)blockIdx.x * 256 + threadIdx.x) * 4;
    const float4 v = *(const float4*)(s + i);
    u16x4 o; o.x = f2b(v.x); o.y = f2b(v.y); o.z = f2b(v.z); o.w = f2b(v.w);
    *(u16x4*)(d + i) = o;
}

// ---- bf16 MFMA GEMM: OUT[m,o] = act(sum_c A[m,c]*W[o,c] + bias[o]) ----
// 128x128 tile, BK=32, 4 waves (2x2), 4x4 frags of 16x16x32 per wave.
// Linear LDS [128][32] bf16, staged via global_load_lds width=16 (m97 structure).
__global__ __launch_bounds__(256) void gemm_bf16(
    const unsigned short* __restrict__ A, const unsigned short* __restrict__ W,
    const float* __restrict__ bias, float* __restrict__ outf,
    unsigned short* __restrict__ outb, int act)
{
    __shared__ unsigned short sA[128 * 32];
    __shared__ unsigned short sB[128 * 32];
    const int tid = threadIdx.x;
    const int l = tid & 63;
    const int w = tid >> 6;
    const int wr = w >> 1, wc = w & 1;
    const int row0 = blockIdx.y * 128, col0 = blockIdx.x * 128;
    f32x4 acc[4][4];
    #pragma unroll
    for (int m = 0; m < 4; ++m)
        #pragma unroll
        for (int n = 0; n < 4; ++n)
            acc[m][n] = (f32x4){0.f, 0.f, 0.f, 0.f};

    for (int kt = 0; kt < C_; kt += 32) {
        #pragma unroll
        for (int it = 0; it < 2; ++it) {
            const int li = it * 256 + tid;
            const unsigned short* ga = A + (size_t)(row0 + (li >> 2)) * C_ + kt + ((li & 3) << 3);
            const unsigned short* gw = W + (size_t)(col0 + (li >> 2)) * C_ + kt + ((li & 3) << 3);
            // wave-uniform LDS base + lane*16B (linear layout matches source order)
            __builtin_amdgcn_global_load_lds(
                (const __attribute__((address_space(1))) void*)ga,
                (__attribute__((address_space(3))) void*)(sA + ((it * 256 + (w << 6)) << 3)),
                16, 0, 0);
            __builtin_amdgcn_global_load_lds(
                (const __attribute__((address_space(1))) void*)gw,
                (__attribute__((address_space(3))) void*)(sB + ((it * 256 + (w << 6)) << 3)),
                16, 0, 0);
        }
        __syncthreads();
        bf16x8 aF[4], bF[4];
        #pragma unroll
        for (int m = 0; m < 4; ++m)
            aF[m] = *(const bf16x8*)&sA[(wr * 64 + m * 16 + (l & 15)) * 32 + ((l >> 4) << 3)];
        #pragma unroll
        for (int n = 0; n < 4; ++n)
            bF[n] = *(const bf16x8*)&sB[(wc * 64 + n * 16 + (l & 15)) * 32 + ((l >> 4) << 3)];
        #pragma unroll
        for (int m = 0; m < 4; ++m)
            #pragma unroll
            for (int n = 0; n < 4; ++n)
                acc[m][n] = __builtin_amdgcn_mfma_f32_16x16x32_bf16(aF[m], bF[n], acc[m][n], 0, 0, 0);
        __syncthreads();
    }
    // epilogue: C/D layout col=lane&15, row=(lane>>4)*4+r
    #pragma unroll
    for (int m = 0; m < 4; ++m) {
        #pragma unroll
        for (int n = 0; n < 4; ++n) {
            const int col = col0 + wc * 64 + n * 16 + (l & 15);
            const float bv = bias ? bias[col] : 0.f;
            #pragma unroll
            for (int r = 0; r < 4; ++r) {
                const int row = row0 + wr * 64 + m * 16 + ((l >> 4) << 2) + r;
                float v = acc[m][n][r] + bv;
                if (act) v = gelu_exact(v);
                if (outf) outf[(size_t)row * C_ + col] = v;
                if (outb) outb[(size_t)row * C_ + col] = f2b(v);
            }
        }
    }
}

// ---- kk/ktv partials: blockIdx = bh*4 + chunk (512 rows each) ----
__global__ __launch_bounds__(256) void kkv_kernel(
    const unsigned short* __restrict__ k, const unsigned short* __restrict__ v,
    float* __restrict__ kkp, float* __restrict__ ktvp)
{
    __shared__ float sK[32][68];
    __shared__ float sV[32][68];
    const int g = blockIdx.x;
    const int bh = g >> 2, chunk = g & 3;
    const int b = bh >> 3, h = bh & 7;
    const int tid = threadIdx.x;
    const int d0 = (tid >> 4) << 2;
    const int e0 = (tid & 15) << 2;
    const int lr = tid >> 4;          // 0..15
    const int lc = (tid & 15) << 2;   // 0..60
    const unsigned short* kb = k + (size_t)b * N_ * C_ + h * D_;
    const unsigned short* vb = v + (size_t)b * N_ * C_ + h * D_;
    float akk[4][4] = {{0.f}}, akv[4][4] = {{0.f}};
    const int nc0 = chunk * 512;
    for (int nc = nc0; nc < nc0 + 512; nc += 32) {
        #pragma unroll
        for (int it = 0; it < 2; ++it) {
            const int r = lr + it * 16;
            const u16x4 ku = *(const u16x4*)(kb + (size_t)(nc + r) * C_ + lc);
            const u16x4 vu = *(const u16x4*)(vb + (size_t)(nc + r) * C_ + lc);
            sK[r][lc + 0] = b2f(ku.x); sK[r][lc + 1] = b2f(ku.y);
            sK[r][lc + 2] = b2f(ku.z); sK[r][lc + 3] = b2f(ku.w);
            sV[r][lc + 0] = b2f(vu.x); sV[r][lc + 1] = b2f(vu.y);
            sV[r][lc + 2] = b2f(vu.z); sV[r][lc + 3] = b2f(vu.w);
        }
        __syncthreads();
        #pragma unroll 8
        for (int nn = 0; nn < 32; ++nn) {
            const float4 kd = *(const float4*)&sK[nn][d0];
            const float4 ke = *(const float4*)&sK[nn][e0];
            const float4 ve = *(const float4*)&sV[nn][e0];
            const float kdv[4] = {kd.x, kd.y, kd.z, kd.w};
            const float kev[4] = {ke.x, ke.y, ke.z, ke.w};
            const float vev[4] = {ve.x, ve.y, ve.z, ve.w};
            #pragma unroll
            for (int i = 0; i < 4; ++i)
                #pragma unroll
                for (int j = 0; j < 4; ++j) {
                    akk[i][j] = fmaf(kdv[i], kev[j], akk[i][j]);
                    akv[i][j] = fmaf(kdv[i], vev[j], akv[i][j]);
                }
        }
        __syncthreads();
    }
    #pragma unroll
    for (int i = 0; i < 4; ++i) {
        float4 o1; o1.x = akk[i][0]; o1.y = akk[i][1]; o1.z = akk[i][2]; o1.w = akk[i][3];
        *(float4*)(kkp + (size_t)g * 4096 + (size_t)(d0 + i) * 64 + e0) = o1;
        float4 o2; o2.x = akv[i][0]; o2.y = akv[i][1]; o2.z = akv[i][2]; o2.w = akv[i][3];
        *(float4*)(ktvp + (size_t)g * 4096 + (size_t)(d0 + i) * 64 + e0) = o2;
    }
}

__global__ __launch_bounds__(256) void reduce4_kernel(
    const float* __restrict__ kkp, const float* __restrict__ ktvp,
    float* __restrict__ kkb, float* __restrict__ ktvb)
{
    const int gid = blockIdx.x * 256 + threadIdx.x;   // 0 .. 2*524288-1
    const int arr = gid >> 19;
    const int i = gid & ((1 << 19) - 1);
    const int bh = i >> 12;
    const int e = i & 4095;
    const float* src = (arr ? ktvp : kkp) + ((size_t)(bh * 4) << 12) + e;
    const float s = src[0] + src[4096] + src[8192] + src[12288];
    (arr ? ktvb : kkb)[((size_t)bh << 12) + e] = s;
}

// Gauss-Jordan (SPD, no pivot) + column softmax. 256 threads: update loop split 4x.
__global__ __launch_bounds__(256) void solve_kernel(
    const float* __restrict__ kkb, const float* __restrict__ ktvb,
    float* __restrict__ attn)
{
    __shared__ float Mg[64][130];
    __shared__ float fac[64];
    const int bh = blockIdx.x;
    const int tid = threadIdx.x;
    for (int idx = tid; idx < 4096; idx += 256) {
        const int r = idx >> 6, j = idx & 63;
        Mg[r][j]      = kkb[(size_t)bh * 4096 + idx];
        Mg[r][64 + j] = ktvb[(size_t)bh * 4096 + idx];
    }
    __syncthreads();
    const int j = tid & 63, wv = tid >> 6;
    for (int i = 0; i < 64; ++i) {
        if (tid < 64) fac[tid] = Mg[tid][i];
        __syncthreads();
        if (wv == 0) {
            const float pinv = 1.0f / fac[i];
            Mg[i][j]      *= pinv;
            Mg[i][64 + j] *= pinv;
        }
        __syncthreads();
        const float mia = Mg[i][j], mib = Mg[i][64 + j];
        for (int r = wv; r < 64; r += 4) {
            if (r != i) {
                const float f = fac[r];
                Mg[r][j]      -= f * mia;
                Mg[r][64 + j] -= f * mib;
            }
        }
        __syncthreads();
    }
    if (tid < 64) {
        float mx = -1e30f;
        for (int r = 0; r < 64; ++r) mx = fmaxf(mx, Mg[r][64 + j]);
        float s = 0.f;
        for (int r = 0; r < 64; ++r) {
            const float e = expf(Mg[r][64 + j] - mx);
            Mg[r][64 + j] = e;
            s += e;
        }
        const float inv = 1.0f / s;
        for (int r = 0; r < 64; ++r) Mg[r][64 + j] *= inv;
    }
    __syncthreads();
    for (int idx = tid; idx < 4096; idx += 256) {
        const int r = idx >> 6, jj = idx & 63;
        attn[(size_t)bh * 4096 + idx] = Mg[r][64 + jj];
    }
}

// o[n,e] = sum_d q[n,d] * attn[d,e], per (b,h), in-place on q (f32).
__global__ __launch_bounds__(256) void apply_kernel(
    float* __restrict__ q, const float* __restrict__ attn)
{
    __shared__ float sQT[64][68];  // [d][row]
    __shared__ float sAt[64][68];  // [d][e]
    const int t = blockIdx.x;
    const int nb = t & 31, h = (t >> 5) & 7, b = t >> 8;
    const int tid = threadIdx.x;
    const size_t base = ((size_t)(b * N_ + nb * 64)) * C_ + h * D_;
    const float* ap = attn + (size_t)(b * H_ + h) * 4096;
    {
        const int lr = tid >> 4, lc = (tid & 15) << 2;
        #pragma unroll
        for (int it = 0; it < 4; ++it) {
            const int dd = lr + it * 16;
            *(float4*)&sAt[dd][lc] = *(const float4*)(ap + (size_t)dd * 64 + lc);
        }
        const int qr = tid >> 2, qf = tid & 3;
        #pragma unroll
        for (int it = 0; it < 4; ++it) {
            const int cc = (qf + it * 4) << 2;
            const float4 a = *(const float4*)(q + base + (size_t)qr * C_ + cc);
            sQT[cc + 0][qr] = a.x; sQT[cc + 1][qr] = a.y;
            sQT[cc + 2][qr] = a.z; sQT[cc + 3][qr] = a.w;
        }
    }
    __syncthreads();
    const int r0 = (tid >> 4) << 2, e0 = (tid & 15) << 2;
    float acc[4][4] = {{0.f}};
    #pragma unroll 8
    for (int dd = 0; dd < 64; ++dd) {
        const float4 qa = *(const float4*)&sQT[dd][r0];
        const float4 av = *(const float4*)&sAt[dd][e0];
        const float qv[4] = {qa.x, qa.y, qa.z, qa.w};
        const float aw[4] = {av.x, av.y, av.z, av.w};
        #pragma unroll
        for (int i = 0; i < 4; ++i)
            #pragma unroll
            for (int jj = 0; jj < 4; ++jj)
                acc[i][jj] = fmaf(qv[i], aw[jj], acc[i][jj]);
    }
    #pragma unroll
    for (int i = 0; i < 4; ++i) {
        float4 o4; o4.x = acc[i][0]; o4.y = acc[i][1]; o4.z = acc[i][2]; o4.w = acc[i][3];
        *(float4*)(q + base + (size_t)(r0 + i) * C_ + e0) = o4;
    }
}

// LayerNorm over last dim (512); reads f32, writes bf16 only.
__global__ __launch_bounds__(256) void ln_kernel(
    const float* __restrict__ o, const float* __restrict__ w,
    const float* __restrict__ bias, unsigned short* __restrict__ ob)
{
    const int wv   = threadIdx.x >> 6;
    const int lane = threadIdx.x & 63;
    const size_t m = (size_t)blockIdx.x * 4 + wv;
    const float* p = o + m * C_ + lane * 8;
    float4 v0 = *(const float4*)p;
    float4 v1 = *(const float4*)(p + 4);
    float s = v0.x + v0.y + v0.z + v0.w + v1.x + v1.y + v1.z + v1.w;
    float q = v0.x * v0.x + v0.y * v0.y + v0.z * v0.z + v0.w * v0.w
            + v1.x * v1.x + v1.y * v1.y + v1.z * v1.z + v1.w * v1.w;
    #pragma unroll
    for (int off = 1; off < 64; off <<= 1) {
        s += __shfl_xor(s, off, 64);
        q += __shfl_xor(q, off, 64);
    }
    const float mean = s * (1.0f / C_);
    const float var  = q * (1.0f / C_) - mean * mean;
    const float rstd = rsqrtf(var + 1e-6f);
    const float4 w0 = *(const float4*)(w + lane * 8);
    const float4 w1 = *(const float4*)(w + lane * 8 + 4);
    const float4 b0 = *(const float4*)(bias + lane * 8);
    const float4 b1 = *(const float4*)(bias + lane * 8 + 4);
    u16x8 ou;
    ou.s0 = f2b((v0.x - mean) * rstd * w0.x + b0.x);
    ou.s1 = f2b((v0.y - mean) * rstd * w0.y + b0.y);
    ou.s2 = f2b((v0.z - mean) * rstd * w0.z + b0.z);
    ou.s3 = f2b((v0.w - mean) * rstd * w0.w + b0.w);
    ou.s4 = f2b((v1.x - mean) * rstd * w1.x + b1.x);
    ou.s5 = f2b((v1.y - mean) * rstd * w1.y + b1.y);
    ou.s6 = f2b((v1.z - mean) * rstd * w1.z + b1.z);
    ou.s7 = f2b((v1.w - mean) * rstd * w1.w + b1.w);
    *(u16x8*)(ob + m * C_ + lane * 8) = ou;
}

// g[m,c] = (depthwise-conv11(a) + db) * vv, bf16 in, bf16 out, f32 accum.
__global__ __launch_bounds__(256) void dwmul_kernel(
    const unsigned short* __restrict__ a, const unsigned short* __restrict__ vv,
    const float* __restrict__ dw, const float* __restrict__ db,
    unsigned short* __restrict__ g)
{
    const int gid = blockIdx.x * 256 + threadIdx.x;
    const int m = gid >> 7;
    const int c = (gid & 127) << 2;
    const int b = m >> 11;
    const int n = m & 2047;
    const float4 db4 = *(const float4*)(db + c);
    float accx = db4.x, accy = db4.y, accz = db4.z, accw = db4.w;
    const unsigned short* abase = a + ((size_t)b * N_) * C_ + c;
    #pragma unroll
    for (int t = 0; t < 11; ++t) {
        const int nn = n + t - 5;
        if (nn >= 0 && nn < N_) {
            const u16x4 a4 = *(const u16x4*)(abase + (size_t)nn * C_);
            accx = fmaf(b2f(a4.x), dw[(c + 0) * 11 + t], accx);
            accy = fmaf(b2f(a4.y), dw[(c + 1) * 11 + t], accy);
            accz = fmaf(b2f(a4.z), dw[(c + 2) * 11 + t], accz);
            accw = fmaf(b2f(a4.w), dw[(c + 3) * 11 + t], accw);
        }
    }
    const u16x4 v4 = *(const u16x4*)(vv + (size_t)m * C_ + c);
    u16x4 o4;
    o4.x = f2b(accx * b2f(v4.x)); o4.y = f2b(accy * b2f(v4.y));
    o4.z = f2b(accz * b2f(v4.z)); o4.w = f2b(accw * b2f(v4.w));
    *(u16x4*)(g + (size_t)m * C_ + c) = o4;
}

extern "C" void kernel_launch(void* const* d_in, const int* in_sizes, int n_in,
                              void* d_out, int out_size, void* d_ws, size_t ws_size,
                              hipStream_t stream)
{
    (void)in_sizes; (void)n_in; (void)out_size; (void)ws_size;
    const float* x      = (const float*)d_in[0];
    const float* wq     = (const float*)d_in[1];
    const float* wk     = (const float*)d_in[2];
    const float* wv     = (const float*)d_in[3];
    const float* ln_w   = (const float*)d_in[4];
    const float* ln_b   = (const float*)d_in[5];
    const float* ava1_w = (const float*)d_in[6];
    const float* ava1_b = (const float*)d_in[7];
    const float* dw_w   = (const float*)d_in[8];
    const float* dw_b   = (const float*)d_in[9];
    const float* v_w    = (const float*)d_in[10];
    const float* v_b    = (const float*)d_in[11];
    const float* proj_w = (const float*)d_in[12];
    const float* proj_b = (const float*)d_in[13];
    const float* out_w  = (const float*)d_in[14];
    const float* out_b  = (const float*)d_in[15];

    // workspace layout (bytes): 3x 33.5MB bf16 act + 7x 0.5MB bf16 w + partials + small
    char* wsb = (char*)d_ws;
    unsigned short* xb = (unsigned short*)wsb;                    // [M_*C_] bf16
    unsigned short* kb = xb + (size_t)M_ * C_;
    unsigned short* vb = kb + (size_t)M_ * C_;
    unsigned short* wtb = vb + (size_t)M_ * C_;                   // 7 weights
    unsigned short* wqb = wtb + 0ULL * C_ * C_;
    unsigned short* wkb = wtb + 1ULL * C_ * C_;
    unsigned short* wvb = wtb + 2ULL * C_ * C_;
    unsigned short* wab = wtb + 3ULL * C_ * C_;
    unsigned short* wvv = wtb + 4ULL * C_ * C_;
    unsigned short* wpb = wtb + 5ULL * C_ * C_;
    unsigned short* wob = wtb + 6ULL * C_ * C_;
    float* kkp   = (float*)(wtb + 7ULL * C_ * C_);                // [128*4][4096]
    float* ktvp  = kkp + 512ULL * 4096;
    float* kkb   = ktvp + 512ULL * 4096;                          // [128][4096]
    float* ktvb  = kkb + 128ULL * 4096;
    float* attnb = ktvb + 128ULL * 4096;
    float* qbuf  = (float*)d_out;                                 // q -> o (f32)

    // aliases (lifetimes disjoint)
    unsigned short* ob  = xb;   // LN output (x dead after q/k/v GEMMs)
    unsigned short* ab  = kb;   // gelu branch (k dead after kkv)
    unsigned short* vvb = vb;   // v branch   (v dead after kkv)
    unsigned short* gb  = xb;   // gate out   (ob dead after a/vv GEMMs)
    unsigned short* pb  = kb;   // proj out   (ab dead after dwmul)

    convx_kernel<<<(M_ * C_) / 1024, 256, 0, stream>>>(x, xb);
    convw_kernel<<<dim3((C_ * C_) / 1024, 7), 256, 0, stream>>>(
        wq, wk, wv, ava1_w, v_w, proj_w, out_w, wtb);

    dim3 gg(C_ / 128, M_ / 128);  // (4, 256)
    gemm_bf16<<<gg, 256, 0, stream>>>(xb, wqb, nullptr, qbuf, nullptr, 0);
    gemm_bf16<<<gg, 256, 0, stream>>>(xb, wkb, nullptr, nullptr, kb, 0);
    gemm_bf16<<<gg, 256, 0, stream>>>(xb, wvb, nullptr, nullptr, vb, 0);
    kkv_kernel<<<B_ * H_ * 4, 256, 0, stream>>>(kb, vb, kkp, ktvp);
    reduce4_kernel<<<4096, 256, 0, stream>>>(kkp, ktvp, kkb, ktvb);
    solve_kernel<<<B_ * H_, 256, 0, stream>>>(kkb, ktvb, attnb);
    apply_kernel<<<B_ * H_ * (N_ / 64), 256, 0, stream>>>(qbuf, attnb);
    ln_kernel<<<M_ / 4, 256, 0, stream>>>(qbuf, ln_w, ln_b, ob);
    gemm_bf16<<<gg, 256, 0, stream>>>(ob, wab, ava1_b, nullptr, ab, 1);      // gelu
    gemm_bf16<<<gg, 256, 0, stream>>>(ob, wvv, v_b, nullptr, vvb, 0);
    dwmul_kernel<<<(M_ * 128) / 256, 256, 0, stream>>>(ab, vvb, dw_w, dw_b, gb);
    gemm_bf16<<<gg, 256, 0, stream>>>(gb, wpb, proj_b, nullptr, pb, 0);
    gemm_bf16<<<gg, 256, 0, stream>>>(pb, wob, out_b, qbuf, nullptr, 0);     // f32 -> d_out
}

// Round 4
// 685.798 us; speedup vs baseline: 3.6046x; 1.2227x over previous
//
#include <hip/hip_runtime.h>
#include <hip/hip_bf16.h>
#include <math.h>

#define B_ 16
#define N_ 2048
#define C_ 512
#define H_ 8
#define D_ 64
#define M_ (B_ * N_)   // 32768
#define NT_ 16         // output rows per thread in dwmul

typedef __attribute__((ext_vector_type(8))) __bf16 bf16x8;
typedef __attribute__((ext_vector_type(4))) float f32x4;
typedef __attribute__((ext_vector_type(4))) unsigned short u16x4;
typedef __attribute__((ext_vector_type(8))) unsigned short u16x8;

__device__ __forceinline__ float gelu_exact(float v) {
    return 0.5f * v * (1.0f + erff(v * 0.70710678118654752440f));
}
__device__ __forceinline__ unsigned short f2b(float f) {  // f32 -> bf16 RNE
    unsigned u = __float_as_uint(f);
    return (unsigned short)((u + 0x7fffu + ((u >> 16) & 1u)) >> 16);
}
__device__ __forceinline__ float b2f(unsigned short b) {
    return __uint_as_float(((unsigned)b) << 16);
}

// ---- f32 -> bf16 converters ----
__global__ __launch_bounds__(256) void convx_kernel(
    const float* __restrict__ src, unsigned short* __restrict__ dst)
{
    const size_t i = ((size_t)blockIdx.x * 256 + threadIdx.x) * 4;
    const float4 v = *(const float4*)(src + i);
    u16x4 o; o.x = f2b(v.x); o.y = f2b(v.y); o.z = f2b(v.z); o.w = f2b(v.w);
    *(u16x4*)(dst + i) = o;
}

__global__ __launch_bounds__(256) void convw_kernel(
    const float* w0, const float* w1, const float* w2, const float* w3,
    const float* w4, const float* w5, const float* w6, unsigned short* __restrict__ dst)
{
    const float* srcs[7] = {w0, w1, w2, w3, w4, w5, w6};
    const float* s = srcs[blockIdx.y];
    unsigned short* d = dst + (size_t)blockIdx.y * (C_ * C_);
    const size_t i = ((size_t)blockIdx.x * 256 + threadIdx.x) * 4;
    const float4 v = *(const float4*)(s + i);
    u16x4 o; o.x = f2b(v.x); o.y = f2b(v.y); o.z = f2b(v.z); o.w = f2b(v.w);
    *(u16x4*)(d + i) = o;
}

// ---- bf16 MFMA GEMM: OUT[m,o] = act(sum_c A[m,c]*W[o,c] + bias[o]) ----
// 128x128 tile, BK=32, 4 waves (2x2), 4x4 frags of 16x16x32 per wave.
// Linear LDS [128][32] bf16, staged via global_load_lds width=16 (m97 structure).
__global__ __launch_bounds__(256) void gemm_bf16(
    const unsigned short* __restrict__ A, const unsigned short* __restrict__ W,
    const float* __restrict__ bias, float* __restrict__ outf,
    unsigned short* __restrict__ outb, int act)
{
    __shared__ unsigned short sA[128 * 32];
    __shared__ unsigned short sB[128 * 32];
    const int tid = threadIdx.x;
    const int l = tid & 63;
    const int w = tid >> 6;
    const int wr = w >> 1, wc = w & 1;
    const int row0 = blockIdx.y * 128, col0 = blockIdx.x * 128;
    f32x4 acc[4][4];
    #pragma unroll
    for (int m = 0; m < 4; ++m)
        #pragma unroll
        for (int n = 0; n < 4; ++n)
            acc[m][n] = (f32x4){0.f, 0.f, 0.f, 0.f};

    for (int kt = 0; kt < C_; kt += 32) {
        #pragma unroll
        for (int it = 0; it < 2; ++it) {
            const int li = it * 256 + tid;
            const unsigned short* ga = A + (size_t)(row0 + (li >> 2)) * C_ + kt + ((li & 3) << 3);
            const unsigned short* gw = W + (size_t)(col0 + (li >> 2)) * C_ + kt + ((li & 3) << 3);
            __builtin_amdgcn_global_load_lds(
                (const __attribute__((address_space(1))) void*)ga,
                (__attribute__((address_space(3))) void*)(sA + ((it * 256 + (w << 6)) << 3)),
                16, 0, 0);
            __builtin_amdgcn_global_load_lds(
                (const __attribute__((address_space(1))) void*)gw,
                (__attribute__((address_space(3))) void*)(sB + ((it * 256 + (w << 6)) << 3)),
                16, 0, 0);
        }
        __syncthreads();
        bf16x8 aF[4], bF[4];
        #pragma unroll
        for (int m = 0; m < 4; ++m)
            aF[m] = *(const bf16x8*)&sA[(wr * 64 + m * 16 + (l & 15)) * 32 + ((l >> 4) << 3)];
        #pragma unroll
        for (int n = 0; n < 4; ++n)
            bF[n] = *(const bf16x8*)&sB[(wc * 64 + n * 16 + (l & 15)) * 32 + ((l >> 4) << 3)];
        #pragma unroll
        for (int m = 0; m < 4; ++m)
            #pragma unroll
            for (int n = 0; n < 4; ++n)
                acc[m][n] = __builtin_amdgcn_mfma_f32_16x16x32_bf16(aF[m], bF[n], acc[m][n], 0, 0, 0);
        __syncthreads();
    }
    #pragma unroll
    for (int m = 0; m < 4; ++m) {
        #pragma unroll
        for (int n = 0; n < 4; ++n) {
            const int col = col0 + wc * 64 + n * 16 + (l & 15);
            const float bv = bias ? bias[col] : 0.f;
            #pragma unroll
            for (int r = 0; r < 4; ++r) {
                const int row = row0 + wr * 64 + m * 16 + ((l >> 4) << 2) + r;
                float v = acc[m][n][r] + bv;
                if (act) v = gelu_exact(v);
                if (outf) outf[(size_t)row * C_ + col] = v;
                if (outb) outb[(size_t)row * C_ + col] = f2b(v);
            }
        }
    }
}

// ---- kk/ktv partials: blockIdx = bh*4 + chunk (512 rows each) ----
__global__ __launch_bounds__(256) void kkv_kernel(
    const unsigned short* __restrict__ k, const unsigned short* __restrict__ v,
    float* __restrict__ kkp, float* __restrict__ ktvp)
{
    __shared__ float sK[32][68];
    __shared__ float sV[32][68];
    const int g = blockIdx.x;
    const int bh = g >> 2, chunk = g & 3;
    const int b = bh >> 3, h = bh & 7;
    const int tid = threadIdx.x;
    const int d0 = (tid >> 4) << 2;
    const int e0 = (tid & 15) << 2;
    const int lr = tid >> 4;          // 0..15
    const int lc = (tid & 15) << 2;   // 0..60
    const unsigned short* kb = k + (size_t)b * N_ * C_ + h * D_;
    const unsigned short* vb = v + (size_t)b * N_ * C_ + h * D_;
    float akk[4][4] = {{0.f}}, akv[4][4] = {{0.f}};
    const int nc0 = chunk * 512;
    for (int nc = nc0; nc < nc0 + 512; nc += 32) {
        #pragma unroll
        for (int it = 0; it < 2; ++it) {
            const int r = lr + it * 16;
            const u16x4 ku = *(const u16x4*)(kb + (size_t)(nc + r) * C_ + lc);
            const u16x4 vu = *(const u16x4*)(vb + (size_t)(nc + r) * C_ + lc);
            sK[r][lc + 0] = b2f(ku.x); sK[r][lc + 1] = b2f(ku.y);
            sK[r][lc + 2] = b2f(ku.z); sK[r][lc + 3] = b2f(ku.w);
            sV[r][lc + 0] = b2f(vu.x); sV[r][lc + 1] = b2f(vu.y);
            sV[r][lc + 2] = b2f(vu.z); sV[r][lc + 3] = b2f(vu.w);
        }
        __syncthreads();
        #pragma unroll 8
        for (int nn = 0; nn < 32; ++nn) {
            const float4 kd = *(const float4*)&sK[nn][d0];
            const float4 ke = *(const float4*)&sK[nn][e0];
            const float4 ve = *(const float4*)&sV[nn][e0];
            const float kdv[4] = {kd.x, kd.y, kd.z, kd.w};
            const float kev[4] = {ke.x, ke.y, ke.z, ke.w};
            const float vev[4] = {ve.x, ve.y, ve.z, ve.w};
            #pragma unroll
            for (int i = 0; i < 4; ++i)
                #pragma unroll
                for (int j = 0; j < 4; ++j) {
                    akk[i][j] = fmaf(kdv[i], kev[j], akk[i][j]);
                    akv[i][j] = fmaf(kdv[i], vev[j], akv[i][j]);
                }
        }
        __syncthreads();
    }
    #pragma unroll
    for (int i = 0; i < 4; ++i) {
        float4 o1; o1.x = akk[i][0]; o1.y = akk[i][1]; o1.z = akk[i][2]; o1.w = akk[i][3];
        *(float4*)(kkp + (size_t)g * 4096 + (size_t)(d0 + i) * 64 + e0) = o1;
        float4 o2; o2.x = akv[i][0]; o2.y = akv[i][1]; o2.z = akv[i][2]; o2.w = akv[i][3];
        *(float4*)(ktvp + (size_t)g * 4096 + (size_t)(d0 + i) * 64 + e0) = o2;
    }
}

__global__ __launch_bounds__(256) void reduce4_kernel(
    const float* __restrict__ kkp, const float* __restrict__ ktvp,
    float* __restrict__ kkb, float* __restrict__ ktvb)
{
    const int gid = blockIdx.x * 256 + threadIdx.x;   // 0 .. 2*524288-1
    const int arr = gid >> 19;
    const int i = gid & ((1 << 19) - 1);
    const int bh = i >> 12;
    const int e = i & 4095;
    const float* src = (arr ? ktvp : kkp) + ((size_t)(bh * 4) << 12) + e;
    const float s = src[0] + src[4096] + src[8192] + src[12288];
    (arr ? ktvb : kkb)[((size_t)bh << 12) + e] = s;
}

// Gauss-Jordan (SPD, no pivot) + column softmax. 256 threads: update loop split 4x.
__global__ __launch_bounds__(256) void solve_kernel(
    const float* __restrict__ kkb, const float* __restrict__ ktvb,
    float* __restrict__ attn)
{
    __shared__ float Mg[64][130];
    __shared__ float fac[64];
    const int bh = blockIdx.x;
    const int tid = threadIdx.x;
    for (int idx = tid; idx < 4096; idx += 256) {
        const int r = idx >> 6, j = idx & 63;
        Mg[r][j]      = kkb[(size_t)bh * 4096 + idx];
        Mg[r][64 + j] = ktvb[(size_t)bh * 4096 + idx];
    }
    __syncthreads();
    const int j = tid & 63, wv = tid >> 6;
    for (int i = 0; i < 64; ++i) {
        if (tid < 64) fac[tid] = Mg[tid][i];
        __syncthreads();
        if (wv == 0) {
            const float pinv = 1.0f / fac[i];
            Mg[i][j]      *= pinv;
            Mg[i][64 + j] *= pinv;
        }
        __syncthreads();
        const float mia = Mg[i][j], mib = Mg[i][64 + j];
        for (int r = wv; r < 64; r += 4) {
            if (r != i) {
                const float f = fac[r];
                Mg[r][j]      -= f * mia;
                Mg[r][64 + j] -= f * mib;
            }
        }
        __syncthreads();
    }
    if (tid < 64) {
        float mx = -1e30f;
        for (int r = 0; r < 64; ++r) mx = fmaxf(mx, Mg[r][64 + j]);
        float s = 0.f;
        for (int r = 0; r < 64; ++r) {
            const float e = expf(Mg[r][64 + j] - mx);
            Mg[r][64 + j] = e;
            s += e;
        }
        const float inv = 1.0f / s;
        for (int r = 0; r < 64; ++r) Mg[r][64 + j] *= inv;
    }
    __syncthreads();
    for (int idx = tid; idx < 4096; idx += 256) {
        const int r = idx >> 6, jj = idx & 63;
        attn[(size_t)bh * 4096 + idx] = Mg[r][64 + jj];
    }
}

// o[n,e] = sum_d q[n,d] * attn[d,e], per (b,h), in-place on q (f32).
__global__ __launch_bounds__(256) void apply_kernel(
    float* __restrict__ q, const float* __restrict__ attn)
{
    __shared__ float sQT[64][68];  // [d][row]
    __shared__ float sAt[64][68];  // [d][e]
    const int t = blockIdx.x;
    const int nb = t & 31, h = (t >> 5) & 7, b = t >> 8;
    const int tid = threadIdx.x;
    const size_t base = ((size_t)(b * N_ + nb * 64)) * C_ + h * D_;
    const float* ap = attn + (size_t)(b * H_ + h) * 4096;
    {
        const int lr = tid >> 4, lc = (tid & 15) << 2;
        #pragma unroll
        for (int it = 0; it < 4; ++it) {
            const int dd = lr + it * 16;
            *(float4*)&sAt[dd][lc] = *(const float4*)(ap + (size_t)dd * 64 + lc);
        }
        const int qr = tid >> 2, qf = tid & 3;
        #pragma unroll
        for (int it = 0; it < 4; ++it) {
            const int cc = (qf + it * 4) << 2;
            const float4 a = *(const float4*)(q + base + (size_t)qr * C_ + cc);
            sQT[cc + 0][qr] = a.x; sQT[cc + 1][qr] = a.y;
            sQT[cc + 2][qr] = a.z; sQT[cc + 3][qr] = a.w;
        }
    }
    __syncthreads();
    const int r0 = (tid >> 4) << 2, e0 = (tid & 15) << 2;
    float acc[4][4] = {{0.f}};
    #pragma unroll 8
    for (int dd = 0; dd < 64; ++dd) {
        const float4 qa = *(const float4*)&sQT[dd][r0];
        const float4 av = *(const float4*)&sAt[dd][e0];
        const float qv[4] = {qa.x, qa.y, qa.z, qa.w};
        const float aw[4] = {av.x, av.y, av.z, av.w};
        #pragma unroll
        for (int i = 0; i < 4; ++i)
            #pragma unroll
            for (int jj = 0; jj < 4; ++jj)
                acc[i][jj] = fmaf(qv[i], aw[jj], acc[i][jj]);
    }
    #pragma unroll
    for (int i = 0; i < 4; ++i) {
        float4 o4; o4.x = acc[i][0]; o4.y = acc[i][1]; o4.z = acc[i][2]; o4.w = acc[i][3];
        *(float4*)(q + base + (size_t)(r0 + i) * C_ + e0) = o4;
    }
}

// LayerNorm over last dim (512); reads f32, writes bf16 only.
__global__ __launch_bounds__(256) void ln_kernel(
    const float* __restrict__ o, const float* __restrict__ w,
    const float* __restrict__ bias, unsigned short* __restrict__ ob)
{
    const int wv   = threadIdx.x >> 6;
    const int lane = threadIdx.x & 63;
    const size_t m = (size_t)blockIdx.x * 4 + wv;
    const float* p = o + m * C_ + lane * 8;
    float4 v0 = *(const float4*)p;
    float4 v1 = *(const float4*)(p + 4);
    float s = v0.x + v0.y + v0.z + v0.w + v1.x + v1.y + v1.z + v1.w;
    float q = v0.x * v0.x + v0.y * v0.y + v0.z * v0.z + v0.w * v0.w
            + v1.x * v1.x + v1.y * v1.y + v1.z * v1.z + v1.w * v1.w;
    #pragma unroll
    for (int off = 1; off < 64; off <<= 1) {
        s += __shfl_xor(s, off, 64);
        q += __shfl_xor(q, off, 64);
    }
    const float mean = s * (1.0f / C_);
    const float var  = q * (1.0f / C_) - mean * mean;
    const float rstd = rsqrtf(var + 1e-6f);
    const float4 w0 = *(const float4*)(w + lane * 8);
    const float4 w1 = *(const float4*)(w + lane * 8 + 4);
    const float4 b0 = *(const float4*)(bias + lane * 8);
    const float4 b1 = *(const float4*)(bias + lane * 8 + 4);
    u16x8 ou;
    ou.s0 = f2b((v0.x - mean) * rstd * w0.x + b0.x);
    ou.s1 = f2b((v0.y - mean) * rstd * w0.y + b0.y);
    ou.s2 = f2b((v0.z - mean) * rstd * w0.z + b0.z);
    ou.s3 = f2b((v0.w - mean) * rstd * w0.w + b0.w);
    ou.s4 = f2b((v1.x - mean) * rstd * w1.x + b1.x);
    ou.s5 = f2b((v1.y - mean) * rstd * w1.y + b1.y);
    ou.s6 = f2b((v1.z - mean) * rstd * w1.z + b1.z);
    ou.s7 = f2b((v1.w - mean) * rstd * w1.w + b1.w);
    *(u16x8*)(ob + m * C_ + lane * 8) = ou;
}

// g = (depthwise-conv11(a) + db) * vv. Register sliding-window: each thread owns
// 4 channels x NT_=16 consecutive rows (never crosses batch edge since 16|2048).
// Circular window win[11] with compile-time indices (full unroll -> registers).
__global__ __launch_bounds__(256) void dwmul_kernel(
    const unsigned short* __restrict__ a, const unsigned short* __restrict__ vv,
    const float* __restrict__ dw, const float* __restrict__ db,
    unsigned short* __restrict__ g)
{
    const int tid = blockIdx.x * 256 + threadIdx.x;   // 262144 threads
    const int cg  = tid & 127;                        // channel quad
    const int mg  = tid >> 7;                         // 16-row group
    const int c   = cg << 2;
    const int m0  = mg * NT_;
    const int b   = m0 >> 11;
    const int n0  = m0 & (N_ - 1);
    // 44 contiguous weight floats for channels c..c+3
    float wt[44];
    #pragma unroll
    for (int i = 0; i < 11; ++i)
        *(float4*)&wt[i * 4] = *(const float4*)(dw + (size_t)c * 11 + i * 4);
    const float4 db4 = *(const float4*)(db + c);
    const unsigned short* ab = a + ((size_t)b * N_) * C_ + c;
    const unsigned short* vp = vv + (size_t)m0 * C_ + c;
    unsigned short* gp = g + (size_t)m0 * C_ + c;

    float win[11][4];
    #pragma unroll
    for (int jj = 0; jj < 11; ++jj) {
        const int nn = n0 - 5 + jj;
        if (nn >= 0 && nn < N_) {
            const u16x4 u = *(const u16x4*)(ab + (size_t)nn * C_);
            win[jj][0] = b2f(u.x); win[jj][1] = b2f(u.y);
            win[jj][2] = b2f(u.z); win[jj][3] = b2f(u.w);
        } else {
            win[jj][0] = 0.f; win[jj][1] = 0.f; win[jj][2] = 0.f; win[jj][3] = 0.f;
        }
    }
    #pragma unroll
    for (int i = 0; i < NT_; ++i) {
        float a0 = db4.x, a1 = db4.y, a2 = db4.z, a3 = db4.w;
        #pragma unroll
        for (int t = 0; t < 11; ++t) {
            const int p = (i + t) % 11;     // compile-time after unroll
            a0 = fmaf(win[p][0], wt[0 * 11 + t], a0);
            a1 = fmaf(win[p][1], wt[1 * 11 + t], a1);
            a2 = fmaf(win[p][2], wt[2 * 11 + t], a2);
            a3 = fmaf(win[p][3], wt[3 * 11 + t], a3);
        }
        const u16x4 v4 = *(const u16x4*)(vp + (size_t)i * C_);
        u16x4 o4;
        o4.x = f2b(a0 * b2f(v4.x)); o4.y = f2b(a1 * b2f(v4.y));
        o4.z = f2b(a2 * b2f(v4.z)); o4.w = f2b(a3 * b2f(v4.w));
        *(u16x4*)(gp + (size_t)i * C_) = o4;
        if (i < NT_ - 1) {
            const int nn = n0 + i + 6;
            const int p = i % 11;           // compile-time after unroll
            if (nn < N_) {
                const u16x4 u = *(const u16x4*)(ab + (size_t)nn * C_);
                win[p][0] = b2f(u.x); win[p][1] = b2f(u.y);
                win[p][2] = b2f(u.z); win[p][3] = b2f(u.w);
            } else {
                win[p][0] = 0.f; win[p][1] = 0.f; win[p][2] = 0.f; win[p][3] = 0.f;
            }
        }
    }
}

extern "C" void kernel_launch(void* const* d_in, const int* in_sizes, int n_in,
                              void* d_out, int out_size, void* d_ws, size_t ws_size,
                              hipStream_t stream)
{
    (void)in_sizes; (void)n_in; (void)out_size; (void)ws_size;
    const float* x      = (const float*)d_in[0];
    const float* wq     = (const float*)d_in[1];
    const float* wk     = (const float*)d_in[2];
    const float* wv     = (const float*)d_in[3];
    const float* ln_w   = (const float*)d_in[4];
    const float* ln_b   = (const float*)d_in[5];
    const float* ava1_w = (const float*)d_in[6];
    const float* ava1_b = (const float*)d_in[7];
    const float* dw_w   = (const float*)d_in[8];
    const float* dw_b   = (const float*)d_in[9];
    const float* v_w    = (const float*)d_in[10];
    const float* v_b    = (const float*)d_in[11];
    const float* proj_w = (const float*)d_in[12];
    const float* proj_b = (const float*)d_in[13];
    const float* out_w  = (const float*)d_in[14];
    const float* out_b  = (const float*)d_in[15];

    char* wsb = (char*)d_ws;
    unsigned short* xb = (unsigned short*)wsb;                    // [M_*C_] bf16
    unsigned short* kb = xb + (size_t)M_ * C_;
    unsigned short* vb = kb + (size_t)M_ * C_;
    unsigned short* wtb = vb + (size_t)M_ * C_;                   // 7 weights
    unsigned short* wqb = wtb + 0ULL * C_ * C_;
    unsigned short* wkb = wtb + 1ULL * C_ * C_;
    unsigned short* wvb = wtb + 2ULL * C_ * C_;
    unsigned short* wab = wtb + 3ULL * C_ * C_;
    unsigned short* wvv = wtb + 4ULL * C_ * C_;
    unsigned short* wpb = wtb + 5ULL * C_ * C_;
    unsigned short* wob = wtb + 6ULL * C_ * C_;
    float* kkp   = (float*)(wtb + 7ULL * C_ * C_);                // [128*4][4096]
    float* ktvp  = kkp + 512ULL * 4096;
    float* kkb   = ktvp + 512ULL * 4096;                          // [128][4096]
    float* ktvb  = kkb + 128ULL * 4096;
    float* attnb = ktvb + 128ULL * 4096;
    float* qbuf  = (float*)d_out;                                 // q -> o (f32)

    unsigned short* ob  = xb;   // LN output (x dead after q/k/v GEMMs)
    unsigned short* ab  = kb;   // gelu branch (k dead after kkv)
    unsigned short* vvb = vb;   // v branch   (v dead after kkv)
    unsigned short* gb  = xb;   // gate out   (ob dead after a/vv GEMMs)
    unsigned short* pb  = kb;   // proj out   (ab dead after dwmul)

    convx_kernel<<<(M_ * C_) / 1024, 256, 0, stream>>>(x, xb);
    convw_kernel<<<dim3((C_ * C_) / 1024, 7), 256, 0, stream>>>(
        wq, wk, wv, ava1_w, v_w, proj_w, out_w, wtb);

    dim3 gg(C_ / 128, M_ / 128);  // (4, 256)
    gemm_bf16<<<gg, 256, 0, stream>>>(xb, wqb, nullptr, qbuf, nullptr, 0);
    gemm_bf16<<<gg, 256, 0, stream>>>(xb, wkb, nullptr, nullptr, kb, 0);
    gemm_bf16<<<gg, 256, 0, stream>>>(xb, wvb, nullptr, nullptr, vb, 0);
    kkv_kernel<<<B_ * H_ * 4, 256, 0, stream>>>(kb, vb, kkp, ktvp);
    reduce4_kernel<<<4096, 256, 0, stream>>>(kkp, ktvp, kkb, ktvb);
    solve_kernel<<<B_ * H_, 256, 0, stream>>>(kkb, ktvb, attnb);
    apply_kernel<<<B_ * H_ * (N_ / 64), 256, 0, stream>>>(qbuf, attnb);
    ln_kernel<<<M_ / 4, 256, 0, stream>>>(qbuf, ln_w, ln_b, ob);
    gemm_bf16<<<gg, 256, 0, stream>>>(ob, wab, ava1_b, nullptr, ab, 1);      // gelu
    gemm_bf16<<<gg, 256, 0, stream>>>(ob, wvv, v_b, nullptr, vvb, 0);
    dwmul_kernel<<<(M_ / NT_ * 128) / 256, 256, 0, stream>>>(ab, vvb, dw_w, dw_b, gb);
    gemm_bf16<<<gg, 256, 0, stream>>>(gb, wpb, proj_b, nullptr, pb, 0);
    gemm_bf16<<<gg, 256, 0, stream>>>(pb, wob, out_b, qbuf, nullptr, 0);     // f32 -> d_out
}

// Round 6
// 609.635 us; speedup vs baseline: 4.0550x; 1.1249x over previous
//
#include <hip/hip_runtime.h>
#include <hip/hip_bf16.h>
#include <math.h>

#define B_ 16
#define N_ 2048
#define C_ 512
#define H_ 8
#define D_ 64
#define M_ (B_ * N_)   // 32768
#define NT_ 16         // output rows per thread in dwmul
#define NS_ITERS 8     // Newton-Schulz iterations (error^2/iter; 7 suffice at cond~2)

typedef __attribute__((ext_vector_type(8))) __bf16 bf16x8;
typedef __attribute__((ext_vector_type(4))) float f32x4;
typedef __attribute__((ext_vector_type(4))) unsigned short u16x4;
typedef __attribute__((ext_vector_type(8))) unsigned short u16x8;

__device__ __forceinline__ float gelu_exact(float v) {
    return 0.5f * v * (1.0f + erff(v * 0.70710678118654752440f));
}
__device__ __forceinline__ unsigned short f2b(float f) {  // f32 -> bf16 RNE
    unsigned u = __float_as_uint(f);
    return (unsigned short)((u + 0x7fffu + ((u >> 16) & 1u)) >> 16);
}
__device__ __forceinline__ float b2f(unsigned short b) {
    return __uint_as_float(((unsigned)b) << 16);
}

union bfu8 { u16x8 u; bf16x8 b; };

// split 8 consecutive f32 into bf16 hi + lo vectors (hi+lo ~ 2^-18 relative)
__device__ __forceinline__ void cvt_hilo(const float* __restrict__ p,
                                         bf16x8& hi, bf16x8& lo) {
    bfu8 h, l;
    #pragma unroll
    for (int i = 0; i < 8; ++i) {
        const float v = p[i];
        const unsigned short hb = f2b(v);
        h.u[i] = hb;
        l.u[i] = f2b(v - b2f(hb));
    }
    hi = h.b; lo = l.b;
}

// acc += (Ah+Al)*(Bh+Bl), dropping Al*Bl (~2^-36)
__device__ __forceinline__ f32x4 mfma3(bf16x8 ah, bf16x8 al,
                                       bf16x8 bh, bf16x8 bl, f32x4 acc) {
    acc = __builtin_amdgcn_mfma_f32_16x16x32_bf16(ah, bh, acc, 0, 0, 0);
    acc = __builtin_amdgcn_mfma_f32_16x16x32_bf16(ah, bl, acc, 0, 0, 0);
    acc = __builtin_amdgcn_mfma_f32_16x16x32_bf16(al, bh, acc, 0, 0, 0);
    return acc;
}

// ---- f32 -> bf16 converters ----
__global__ __launch_bounds__(256) void convx_kernel(
    const float* __restrict__ src, unsigned short* __restrict__ dst)
{
    const size_t i = ((size_t)blockIdx.x * 256 + threadIdx.x) * 4;
    const float4 v = *(const float4*)(src + i);
    u16x4 o; o.x = f2b(v.x); o.y = f2b(v.y); o.z = f2b(v.z); o.w = f2b(v.w);
    *(u16x4*)(dst + i) = o;
}

__global__ __launch_bounds__(256) void convw_kernel(
    const float* w0, const float* w1, const float* w2, const float* w3,
    const float* w4, const float* w5, const float* w6, unsigned short* __restrict__ dst)
{
    const float* srcs[7] = {w0, w1, w2, w3, w4, w5, w6};
    const float* s = srcs[blockIdx.y];
    unsigned short* d = dst + (size_t)blockIdx.y * (C_ * C_);
    const size_t i = ((size_t)blockIdx.x * 256 + threadIdx.x) * 4;
    const float4 v = *(const float4*)(s + i);
    u16x4 o; o.x = f2b(v.x); o.y = f2b(v.y); o.z = f2b(v.z); o.w = f2b(v.w);
    *(u16x4*)(d + i) = o;
}

// ---- bf16 MFMA GEMM: OUT[m,o] = act(sum_c A[m,c]*W[o,c] + bias[o]) ----
__global__ __launch_bounds__(256) void gemm_bf16(
    const unsigned short* __restrict__ A, const unsigned short* __restrict__ W,
    const float* __restrict__ bias, float* __restrict__ outf,
    unsigned short* __restrict__ outb, int act)
{
    __shared__ unsigned short sA[128 * 32];
    __shared__ unsigned short sB[128 * 32];
    const int tid = threadIdx.x;
    const int l = tid & 63;
    const int w = tid >> 6;
    const int wr = w >> 1, wc = w & 1;
    const int row0 = blockIdx.y * 128, col0 = blockIdx.x * 128;
    f32x4 acc[4][4];
    #pragma unroll
    for (int m = 0; m < 4; ++m)
        #pragma unroll
        for (int n = 0; n < 4; ++n)
            acc[m][n] = (f32x4){0.f, 0.f, 0.f, 0.f};

    for (int kt = 0; kt < C_; kt += 32) {
        #pragma unroll
        for (int it = 0; it < 2; ++it) {
            const int li = it * 256 + tid;
            const unsigned short* ga = A + (size_t)(row0 + (li >> 2)) * C_ + kt + ((li & 3) << 3);
            const unsigned short* gw = W + (size_t)(col0 + (li >> 2)) * C_ + kt + ((li & 3) << 3);
            __builtin_amdgcn_global_load_lds(
                (const __attribute__((address_space(1))) void*)ga,
                (__attribute__((address_space(3))) void*)(sA + ((it * 256 + (w << 6)) << 3)),
                16, 0, 0);
            __builtin_amdgcn_global_load_lds(
                (const __attribute__((address_space(1))) void*)gw,
                (__attribute__((address_space(3))) void*)(sB + ((it * 256 + (w << 6)) << 3)),
                16, 0, 0);
        }
        __syncthreads();
        bf16x8 aF[4], bF[4];
        #pragma unroll
        for (int m = 0; m < 4; ++m)
            aF[m] = *(const bf16x8*)&sA[(wr * 64 + m * 16 + (l & 15)) * 32 + ((l >> 4) << 3)];
        #pragma unroll
        for (int n = 0; n < 4; ++n)
            bF[n] = *(const bf16x8*)&sB[(wc * 64 + n * 16 + (l & 15)) * 32 + ((l >> 4) << 3)];
        #pragma unroll
        for (int m = 0; m < 4; ++m)
            #pragma unroll
            for (int n = 0; n < 4; ++n)
                acc[m][n] = __builtin_amdgcn_mfma_f32_16x16x32_bf16(aF[m], bF[n], acc[m][n], 0, 0, 0);
        __syncthreads();
    }
    #pragma unroll
    for (int m = 0; m < 4; ++m) {
        #pragma unroll
        for (int n = 0; n < 4; ++n) {
            const int col = col0 + wc * 64 + n * 16 + (l & 15);
            const float bv = bias ? bias[col] : 0.f;
            #pragma unroll
            for (int r = 0; r < 4; ++r) {
                const int row = row0 + wr * 64 + m * 16 + ((l >> 4) << 2) + r;
                float v = acc[m][n][r] + bv;
                if (act) v = gelu_exact(v);
                if (outf) outf[(size_t)row * C_ + col] = v;
                if (outb) outb[(size_t)row * C_ + col] = f2b(v);
            }
        }
    }
}

// ---- kk/ktv partials: blockIdx = bh*4 + chunk (512 rows each) ----
__global__ __launch_bounds__(256) void kkv_kernel(
    const unsigned short* __restrict__ k, const unsigned short* __restrict__ v,
    float* __restrict__ kkp, float* __restrict__ ktvp)
{
    __shared__ float sK[32][68];
    __shared__ float sV[32][68];
    const int g = blockIdx.x;
    const int bh = g >> 2, chunk = g & 3;
    const int b = bh >> 3, h = bh & 7;
    const int tid = threadIdx.x;
    const int d0 = (tid >> 4) << 2;
    const int e0 = (tid & 15) << 2;
    const int lr = tid >> 4;          // 0..15
    const int lc = (tid & 15) << 2;   // 0..60
    const unsigned short* kb = k + (size_t)b * N_ * C_ + h * D_;
    const unsigned short* vb = v + (size_t)b * N_ * C_ + h * D_;
    float akk[4][4] = {{0.f}}, akv[4][4] = {{0.f}};
    const int nc0 = chunk * 512;
    for (int nc = nc0; nc < nc0 + 512; nc += 32) {
        #pragma unroll
        for (int it = 0; it < 2; ++it) {
            const int r = lr + it * 16;
            const u16x4 ku = *(const u16x4*)(kb + (size_t)(nc + r) * C_ + lc);
            const u16x4 vu = *(const u16x4*)(vb + (size_t)(nc + r) * C_ + lc);
            sK[r][lc + 0] = b2f(ku.x); sK[r][lc + 1] = b2f(ku.y);
            sK[r][lc + 2] = b2f(ku.z); sK[r][lc + 3] = b2f(ku.w);
            sV[r][lc + 0] = b2f(vu.x); sV[r][lc + 1] = b2f(vu.y);
            sV[r][lc + 2] = b2f(vu.z); sV[r][lc + 3] = b2f(vu.w);
        }
        __syncthreads();
        #pragma unroll 8
        for (int nn = 0; nn < 32; ++nn) {
            const float4 kd = *(const float4*)&sK[nn][d0];
            const float4 ke = *(const float4*)&sK[nn][e0];
            const float4 ve = *(const float4*)&sV[nn][e0];
            const float kdv[4] = {kd.x, kd.y, kd.z, kd.w};
            const float kev[4] = {ke.x, ke.y, ke.z, ke.w};
            const float vev[4] = {ve.x, ve.y, ve.z, ve.w};
            #pragma unroll
            for (int i = 0; i < 4; ++i)
                #pragma unroll
                for (int j = 0; j < 4; ++j) {
                    akk[i][j] = fmaf(kdv[i], kev[j], akk[i][j]);
                    akv[i][j] = fmaf(kdv[i], vev[j], akv[i][j]);
                }
        }
        __syncthreads();
    }
    #pragma unroll
    for (int i = 0; i < 4; ++i) {
        float4 o1; o1.x = akk[i][0]; o1.y = akk[i][1]; o1.z = akk[i][2]; o1.w = akk[i][3];
        *(float4*)(kkp + (size_t)g * 4096 + (size_t)(d0 + i) * 64 + e0) = o1;
        float4 o2; o2.x = akv[i][0]; o2.y = akv[i][1]; o2.z = akv[i][2]; o2.w = akv[i][3];
        *(float4*)(ktvp + (size_t)g * 4096 + (size_t)(d0 + i) * 64 + e0) = o2;
    }
}

__global__ __launch_bounds__(256) void reduce4_kernel(
    const float* __restrict__ kkp, const float* __restrict__ ktvp,
    float* __restrict__ kkb, float* __restrict__ ktvb)
{
    const int gid = blockIdx.x * 256 + threadIdx.x;   // 0 .. 2*524288-1
    const int arr = gid >> 19;
    const int i = gid & ((1 << 19) - 1);
    const int bh = i >> 12;
    const int e = i & 4095;
    const float* src = (arr ? ktvp : kkp) + ((size_t)(bh * 4) << 12) + e;
    const float s = src[0] + src[4096] + src[8192] + src[12288];
    (arr ? ktvb : kkb)[((size_t)bh << 12) + e] = s;
}

// ---- Newton-Schulz solve (f32 state, split-bf16 MFMA) + column softmax ----
// attn = softmax_rows( inv(kk) @ ktv ). kk SPD (Gram of N=2048 rows, cond~2).
// X0 = I/||A||inf; X <- X(2I - AX). All matrices kept f32 in LDS; every MFMA
// operand split into bf16 hi+lo, product = 3 MFMAs (~2^-18 rel per product).
// S and X written both row-major and transposed => no symmetry assumptions.
__global__ __launch_bounds__(256) void solve_kernel(
    const float* __restrict__ kkb, const float* __restrict__ ktvb,
    float* __restrict__ attn)
{
    __shared__ float sX [64 * 68];   // X row-major
    __shared__ float sXT[64 * 68];   // X transposed
    __shared__ float sST[64 * 68];   // S transposed
    __shared__ float sTT[64 * 68];   // T transposed
    __shared__ float sP [64 * 66 + 64];  // P + scratch (psum / c at [4224])

    const int tid = threadIdx.x;
    const int bh = blockIdx.x;
    const float* Ag = kkb + (size_t)bh * 4096;
    const float* Tg = ktvb + (size_t)bh * 4096;

    // row-abs partial sums of A + stage T^T (f32)
    const int lrow = tid >> 2, lcol0 = (tid & 3) * 16;
    {
        float asum = 0.f;
        #pragma unroll
        for (int i = 0; i < 16; i += 4) {
            const float4 va = *(const float4*)(Ag + lrow * 64 + lcol0 + i);
            asum += fabsf(va.x) + fabsf(va.y) + fabsf(va.z) + fabsf(va.w);
            const float4 vt = *(const float4*)(Tg + lrow * 64 + lcol0 + i);
            sTT[(lcol0 + i + 0) * 68 + lrow] = vt.x;
            sTT[(lcol0 + i + 1) * 68 + lrow] = vt.y;
            sTT[(lcol0 + i + 2) * 68 + lrow] = vt.z;
            sTT[(lcol0 + i + 3) * 68 + lrow] = vt.w;
        }
        sP[tid] = asum;
    }
    __syncthreads();
    if (tid < 64) {
        float rs = sP[tid * 4] + sP[tid * 4 + 1] + sP[tid * 4 + 2] + sP[tid * 4 + 3];
        #pragma unroll
        for (int off = 1; off < 64; off <<= 1)
            rs = fmaxf(rs, __shfl_xor(rs, off, 64));
        if (tid == 0) sP[4224] = 1.0f / rs;
    }
    __syncthreads();
    {
        const float c = sP[4224];
        #pragma unroll
        for (int i = 0; i < 16; ++i) {
            const int col = lcol0 + i;
            const float v = (col == lrow) ? c : 0.f;
            sX [lrow * 68 + col] = v;
            sXT[col * 68 + lrow] = v;
        }
    }
    __syncthreads();

    const int l = tid & 63, w = tid >> 6;
    const int fr = l & 15;          // fragment row (A-op) / col (B-op)
    const int fk = (l >> 4) << 3;   // k offset within 32-chunk
    const int rb = (l >> 4) << 2;   // C/D row base within 16
    // A fragments (hi/lo), loop-invariant, straight from global
    bf16x8 aAh[2], aAl[2];
    {
        float abuf[8];
        #pragma unroll
        for (int ch = 0; ch < 2; ++ch) {
            #pragma unroll
            for (int i = 0; i < 8; ++i)
                abuf[i] = Ag[(w * 16 + fr) * 64 + ch * 32 + fk + i];
            cvt_hilo(abuf, aAh[ch], aAl[ch]);
        }
    }

    for (int it = 0; it < NS_ITERS; ++it) {
        // GEMM1: Y = A * X  (B-op = rows of X^T)
        f32x4 accY[4];
        #pragma unroll
        for (int n = 0; n < 4; ++n) {
            bf16x8 bh0, bl0, bh1, bl1;
            cvt_hilo(&sXT[(n * 16 + fr) * 68 + 0  + fk], bh0, bl0);
            cvt_hilo(&sXT[(n * 16 + fr) * 68 + 32 + fk], bh1, bl1);
            f32x4 a = (f32x4){0.f, 0.f, 0.f, 0.f};
            a = mfma3(aAh[0], aAl[0], bh0, bl0, a);
            a = mfma3(aAh[1], aAl[1], bh1, bl1, a);
            accY[n] = a;
        }
        // S^T[col][row] = 2I - Y[row][col]
        #pragma unroll
        for (int n = 0; n < 4; ++n) {
            const int col = n * 16 + fr;
            #pragma unroll
            for (int r = 0; r < 4; ++r) {
                const int row = w * 16 + rb + r;
                sST[col * 68 + row] = ((row == col) ? 2.0f : 0.0f) - accY[n][r];
            }
        }
        __syncthreads();
        // GEMM2: Xn = X * S  (A-op = rows of X, B-op = rows of S^T)
        bf16x8 aXh[2], aXl[2];
        cvt_hilo(&sX[(w * 16 + fr) * 68 + 0],  aXh[0], aXl[0]);
        cvt_hilo(&sX[(w * 16 + fr) * 68 + 32], aXh[1], aXl[1]);
        // (note: A-op fragment needs cols fk..fk+7 -> re-derive per chunk)
        cvt_hilo(&sX[(w * 16 + fr) * 68 + 0  + fk], aXh[0], aXl[0]);
        cvt_hilo(&sX[(w * 16 + fr) * 68 + 32 + fk], aXh[1], aXl[1]);
        f32x4 accX[4];
        #pragma unroll
        for (int n = 0; n < 4; ++n) {
            bf16x8 bh0, bl0, bh1, bl1;
            cvt_hilo(&sST[(n * 16 + fr) * 68 + 0  + fk], bh0, bl0);
            cvt_hilo(&sST[(n * 16 + fr) * 68 + 32 + fk], bh1, bl1);
            f32x4 a = (f32x4){0.f, 0.f, 0.f, 0.f};
            a = mfma3(aXh[0], aXl[0], bh0, bl0, a);
            a = mfma3(aXh[1], aXl[1], bh1, bl1, a);
            accX[n] = a;
        }
        __syncthreads();   // all reads of sX/sXT done before overwrite
        #pragma unroll
        for (int n = 0; n < 4; ++n) {
            const int col = n * 16 + fr;
            #pragma unroll
            for (int r = 0; r < 4; ++r) {
                const int row = w * 16 + rb + r;
                const float v = accX[n][r];
                sX [row * 68 + col] = v;
                sXT[col * 68 + row] = v;
            }
        }
        __syncthreads();
    }

    // P = X * T  (A-op = rows of X, B-op = rows of T^T)
    {
        bf16x8 aXh[2], aXl[2];
        cvt_hilo(&sX[(w * 16 + fr) * 68 + 0  + fk], aXh[0], aXl[0]);
        cvt_hilo(&sX[(w * 16 + fr) * 68 + 32 + fk], aXh[1], aXl[1]);
        #pragma unroll
        for (int n = 0; n < 4; ++n) {
            bf16x8 bh0, bl0, bh1, bl1;
            cvt_hilo(&sTT[(n * 16 + fr) * 68 + 0  + fk], bh0, bl0);
            cvt_hilo(&sTT[(n * 16 + fr) * 68 + 32 + fk], bh1, bl1);
            f32x4 a = (f32x4){0.f, 0.f, 0.f, 0.f};
            a = mfma3(aXh[0], aXl[0], bh0, bl0, a);
            a = mfma3(aXh[1], aXl[1], bh1, bl1, a);
            const int col = n * 16 + fr;
            #pragma unroll
            for (int r = 0; r < 4; ++r)
                sP[(w * 16 + rb + r) * 66 + col] = a[r];
        }
    }
    __syncthreads();
    // softmax over rows (axis d) per column e = tid
    if (tid < 64) {
        float mx = -1e30f;
        for (int r = 0; r < 64; ++r) mx = fmaxf(mx, sP[r * 66 + tid]);
        float s = 0.f;
        for (int r = 0; r < 64; ++r) {
            const float e = expf(sP[r * 66 + tid] - mx);
            sP[r * 66 + tid] = e;
            s += e;
        }
        const float inv = 1.0f / s;
        for (int r = 0; r < 64; ++r)
            attn[(size_t)bh * 4096 + (size_t)r * 64 + tid] = sP[r * 66 + tid] * inv;
    }
}

// o[n,e] = sum_d q[n,d] * attn[d,e], per (b,h), in-place on q (f32).
__global__ __launch_bounds__(256) void apply_kernel(
    float* __restrict__ q, const float* __restrict__ attn)
{
    __shared__ float sQT[64][68];  // [d][row]
    __shared__ float sAt[64][68];  // [d][e]
    const int t = blockIdx.x;
    const int nb = t & 31, h = (t >> 5) & 7, b = t >> 8;
    const int tid = threadIdx.x;
    const size_t base = ((size_t)(b * N_ + nb * 64)) * C_ + h * D_;
    const float* ap = attn + (size_t)(b * H_ + h) * 4096;
    {
        const int lr = tid >> 4, lc = (tid & 15) << 2;
        #pragma unroll
        for (int it = 0; it < 4; ++it) {
            const int dd = lr + it * 16;
            *(float4*)&sAt[dd][lc] = *(const float4*)(ap + (size_t)dd * 64 + lc);
        }
        const int qr = tid >> 2, qf = tid & 3;
        #pragma unroll
        for (int it = 0; it < 4; ++it) {
            const int cc = (qf + it * 4) << 2;
            const float4 a = *(const float4*)(q + base + (size_t)qr * C_ + cc);
            sQT[cc + 0][qr] = a.x; sQT[cc + 1][qr] = a.y;
            sQT[cc + 2][qr] = a.z; sQT[cc + 3][qr] = a.w;
        }
    }
    __syncthreads();
    const int r0 = (tid >> 4) << 2, e0 = (tid & 15) << 2;
    float acc[4][4] = {{0.f}};
    #pragma unroll 8
    for (int dd = 0; dd < 64; ++dd) {
        const float4 qa = *(const float4*)&sQT[dd][r0];
        const float4 av = *(const float4*)&sAt[dd][e0];
        const float qv[4] = {qa.x, qa.y, qa.z, qa.w};
        const float aw[4] = {av.x, av.y, av.z, av.w};
        #pragma unroll
        for (int i = 0; i < 4; ++i)
            #pragma unroll
            for (int jj = 0; jj < 4; ++jj)
                acc[i][jj] = fmaf(qv[i], aw[jj], acc[i][jj]);
    }
    #pragma unroll
    for (int i = 0; i < 4; ++i) {
        float4 o4; o4.x = acc[i][0]; o4.y = acc[i][1]; o4.z = acc[i][2]; o4.w = acc[i][3];
        *(float4*)(q + base + (size_t)(r0 + i) * C_ + e0) = o4;
    }
}

// LayerNorm over last dim (512); reads f32, writes bf16 only.
__global__ __launch_bounds__(256) void ln_kernel(
    const float* __restrict__ o, const float* __restrict__ w,
    const float* __restrict__ bias, unsigned short* __restrict__ ob)
{
    const int wv   = threadIdx.x >> 6;
    const int lane = threadIdx.x & 63;
    const size_t m = (size_t)blockIdx.x * 4 + wv;
    const float* p = o + m * C_ + lane * 8;
    float4 v0 = *(const float4*)p;
    float4 v1 = *(const float4*)(p + 4);
    float s = v0.x + v0.y + v0.z + v0.w + v1.x + v1.y + v1.z + v1.w;
    float q = v0.x * v0.x + v0.y * v0.y + v0.z * v0.z + v0.w * v0.w
            + v1.x * v1.x + v1.y * v1.y + v1.z * v1.z + v1.w * v1.w;
    #pragma unroll
    for (int off = 1; off < 64; off <<= 1) {
        s += __shfl_xor(s, off, 64);
        q += __shfl_xor(q, off, 64);
    }
    const float mean = s * (1.0f / C_);
    const float var  = q * (1.0f / C_) - mean * mean;
    const float rstd = rsqrtf(var + 1e-6f);
    const float4 w0 = *(const float4*)(w + lane * 8);
    const float4 w1 = *(const float4*)(w + lane * 8 + 4);
    const float4 b0 = *(const float4*)(bias + lane * 8);
    const float4 b1 = *(const float4*)(bias + lane * 8 + 4);
    u16x8 ou;
    ou.s0 = f2b((v0.x - mean) * rstd * w0.x + b0.x);
    ou.s1 = f2b((v0.y - mean) * rstd * w0.y + b0.y);
    ou.s2 = f2b((v0.z - mean) * rstd * w0.z + b0.z);
    ou.s3 = f2b((v0.w - mean) * rstd * w0.w + b0.w);
    ou.s4 = f2b((v1.x - mean) * rstd * w1.x + b1.x);
    ou.s5 = f2b((v1.y - mean) * rstd * w1.y + b1.y);
    ou.s6 = f2b((v1.z - mean) * rstd * w1.z + b1.z);
    ou.s7 = f2b((v1.w - mean) * rstd * w1.w + b1.w);
    *(u16x8*)(ob + m * C_ + lane * 8) = ou;
}

// g = (depthwise-conv11(a) + db) * vv. Register sliding-window.
__global__ __launch_bounds__(256) void dwmul_kernel(
    const unsigned short* __restrict__ a, const unsigned short* __restrict__ vv,
    const float* __restrict__ dw, const float* __restrict__ db,
    unsigned short* __restrict__ g)
{
    const int tid = blockIdx.x * 256 + threadIdx.x;   // 262144 threads
    const int cg  = tid & 127;                        // channel quad
    const int mg  = tid >> 7;                         // 16-row group
    const int c   = cg << 2;
    const int m0  = mg * NT_;
    const int b   = m0 >> 11;
    const int n0  = m0 & (N_ - 1);
    float wt[44];
    #pragma unroll
    for (int i = 0; i < 11; ++i)
        *(float4*)&wt[i * 4] = *(const float4*)(dw + (size_t)c * 11 + i * 4);
    const float4 db4 = *(const float4*)(db + c);
    const unsigned short* ab = a + ((size_t)b * N_) * C_ + c;
    const unsigned short* vp = vv + (size_t)m0 * C_ + c;
    unsigned short* gp = g + (size_t)m0 * C_ + c;

    float win[11][4];
    #pragma unroll
    for (int jj = 0; jj < 11; ++jj) {
        const int nn = n0 - 5 + jj;
        if (nn >= 0 && nn < N_) {
            const u16x4 u = *(const u16x4*)(ab + (size_t)nn * C_);
            win[jj][0] = b2f(u.x); win[jj][1] = b2f(u.y);
            win[jj][2] = b2f(u.z); win[jj][3] = b2f(u.w);
        } else {
            win[jj][0] = 0.f; win[jj][1] = 0.f; win[jj][2] = 0.f; win[jj][3] = 0.f;
        }
    }
    #pragma unroll
    for (int i = 0; i < NT_; ++i) {
        float a0 = db4.x, a1 = db4.y, a2 = db4.z, a3 = db4.w;
        #pragma unroll
        for (int t = 0; t < 11; ++t) {
            const int p = (i + t) % 11;     // compile-time after unroll
            a0 = fmaf(win[p][0], wt[0 * 11 + t], a0);
            a1 = fmaf(win[p][1], wt[1 * 11 + t], a1);
            a2 = fmaf(win[p][2], wt[2 * 11 + t], a2);
            a3 = fmaf(win[p][3], wt[3 * 11 + t], a3);
        }
        const u16x4 v4 = *(const u16x4*)(vp + (size_t)i * C_);
        u16x4 o4;
        o4.x = f2b(a0 * b2f(v4.x)); o4.y = f2b(a1 * b2f(v4.y));
        o4.z = f2b(a2 * b2f(v4.z)); o4.w = f2b(a3 * b2f(v4.w));
        *(u16x4*)(gp + (size_t)i * C_) = o4;
        if (i < NT_ - 1) {
            const int nn = n0 + i + 6;
            const int p = i % 11;           // compile-time after unroll
            if (nn < N_) {
                const u16x4 u = *(const u16x4*)(ab + (size_t)nn * C_);
                win[p][0] = b2f(u.x); win[p][1] = b2f(u.y);
                win[p][2] = b2f(u.z); win[p][3] = b2f(u.w);
            } else {
                win[p][0] = 0.f; win[p][1] = 0.f; win[p][2] = 0.f; win[p][3] = 0.f;
            }
        }
    }
}

extern "C" void kernel_launch(void* const* d_in, const int* in_sizes, int n_in,
                              void* d_out, int out_size, void* d_ws, size_t ws_size,
                              hipStream_t stream)
{
    (void)in_sizes; (void)n_in; (void)out_size; (void)ws_size;
    const float* x      = (const float*)d_in[0];
    const float* wq     = (const float*)d_in[1];
    const float* wk     = (const float*)d_in[2];
    const float* wv     = (const float*)d_in[3];
    const float* ln_w   = (const float*)d_in[4];
    const float* ln_b   = (const float*)d_in[5];
    const float* ava1_w = (const float*)d_in[6];
    const float* ava1_b = (const float*)d_in[7];
    const float* dw_w   = (const float*)d_in[8];
    const float* dw_b   = (const float*)d_in[9];
    const float* v_w    = (const float*)d_in[10];
    const float* v_b    = (const float*)d_in[11];
    const float* proj_w = (const float*)d_in[12];
    const float* proj_b = (const float*)d_in[13];
    const float* out_w  = (const float*)d_in[14];
    const float* out_b  = (const float*)d_in[15];

    char* wsb = (char*)d_ws;
    unsigned short* xb = (unsigned short*)wsb;                    // [M_*C_] bf16
    unsigned short* kb = xb + (size_t)M_ * C_;
    unsigned short* vb = kb + (size_t)M_ * C_;
    unsigned short* wtb = vb + (size_t)M_ * C_;                   // 7 weights
    unsigned short* wqb = wtb + 0ULL * C_ * C_;
    unsigned short* wkb = wtb + 1ULL * C_ * C_;
    unsigned short* wvb = wtb + 2ULL * C_ * C_;
    unsigned short* wab = wtb + 3ULL * C_ * C_;
    unsigned short* wvv = wtb + 4ULL * C_ * C_;
    unsigned short* wpb = wtb + 5ULL * C_ * C_;
    unsigned short* wob = wtb + 6ULL * C_ * C_;
    float* kkp   = (float*)(wtb + 7ULL * C_ * C_);                // [128*4][4096]
    float* ktvp  = kkp + 512ULL * 4096;
    float* kkb   = ktvp + 512ULL * 4096;                          // [128][4096]
    float* ktvb  = kkb + 128ULL * 4096;
    float* attnb = ktvb + 128ULL * 4096;
    float* qbuf  = (float*)d_out;                                 // q -> o (f32)

    unsigned short* ob  = xb;   // LN output (x dead after q/k/v GEMMs)
    unsigned short* ab  = kb;   // gelu branch (k dead after kkv)
    unsigned short* vvb = vb;   // v branch   (v dead after kkv)
    unsigned short* gb  = xb;   // gate out   (ob dead after a/vv GEMMs)
    unsigned short* pb  = kb;   // proj out   (ab dead after dwmul)

    convx_kernel<<<(M_ * C_) / 1024, 256, 0, stream>>>(x, xb);
    convw_kernel<<<dim3((C_ * C_) / 1024, 7), 256, 0, stream>>>(
        wq, wk, wv, ava1_w, v_w, proj_w, out_w, wtb);

    dim3 gg(C_ / 128, M_ / 128);  // (4, 256)
    gemm_bf16<<<gg, 256, 0, stream>>>(xb, wqb, nullptr, qbuf, nullptr, 0);
    gemm_bf16<<<gg, 256, 0, stream>>>(xb, wkb, nullptr, nullptr, kb, 0);
    gemm_bf16<<<gg, 256, 0, stream>>>(xb, wvb, nullptr, nullptr, vb, 0);
    kkv_kernel<<<B_ * H_ * 4, 256, 0, stream>>>(kb, vb, kkp, ktvp);
    reduce4_kernel<<<4096, 256, 0, stream>>>(kkp, ktvp, kkb, ktvb);
    solve_kernel<<<B_ * H_, 256, 0, stream>>>(kkb, ktvb, attnb);
    apply_kernel<<<B_ * H_ * (N_ / 64), 256, 0, stream>>>(qbuf, attnb);
    ln_kernel<<<M_ / 4, 256, 0, stream>>>(qbuf, ln_w, ln_b, ob);
    gemm_bf16<<<gg, 256, 0, stream>>>(ob, wab, ava1_b, nullptr, ab, 1);      // gelu
    gemm_bf16<<<gg, 256, 0, stream>>>(ob, wvv, v_b, nullptr, vvb, 0);
    dwmul_kernel<<<(M_ / NT_ * 128) / 256, 256, 0, stream>>>(ab, vvb, dw_w, dw_b, gb);
    gemm_bf16<<<gg, 256, 0, stream>>>(gb, wpb, proj_b, nullptr, pb, 0);
    gemm_bf16<<<gg, 256, 0, stream>>>(pb, wob, out_b, qbuf, nullptr, 0);     // f32 -> d_out
}